// Round 13
// baseline (43.231 us; speedup 1.0000x reference)
//
#include <hip/hip_runtime.h>

// Problem constants
#define NB 64
#define NL 128
#define NQ 128
#define NE 16384

// ws float layout (fused path: 64 partials; fallback path: 256 partials)
#define WS_TW    0
#define WS_PART  8

// dynamic LDS byte offsets (fused kernel)
#define OFF_PT   0            // ushort [128][136]  P_b^T bf16: PT[q][j] = P_b[j][q]
#define OFF_AT   34816        // ushort [128][136]  A^T  bf16: AT[q][p] = A[p][q]
#define OFF_WF   69632        // float  [128][132]  W fp32 scatter target
#define DYN_BYTES 137216      // 34816*2 + 67584

using short8 = __attribute__((ext_vector_type(8))) short;  // 8 bf16
using f32x4  = __attribute__((ext_vector_type(4))) float;

// fp32 -> bf16 bits, round-to-nearest-even
__device__ inline unsigned short f2bf(float f) {
    const unsigned u = __float_as_uint(f);
    return (unsigned short)((u + 0x7fffu + ((u >> 16) & 1u)) >> 16);
}

__device__ inline short8 pack8(float4 a, float4 b) {
    short8 r;
    r[0] = f2bf(a.x); r[1] = f2bf(a.y); r[2] = f2bf(a.z); r[3] = f2bf(a.w);
    r[4] = f2bf(b.x); r[5] = f2bf(b.y); r[6] = f2bf(b.z); r[7] = f2bf(b.w);
    return r;
}

// ---------------------------------------------------------------------------
// fused: 64 blocks x 1024 threads (16 waves), 137 KB dynamic LDS, 1 block/CU.
// Block b stages ONCE: PT (P_b^T bf16), AT (A^T bf16), WF (fp32 W via one
// edge scan + LDS atomics). Then wave w = (ih = w>>3, qt = w&7) computes
// 4 i-tiles x 1 q-tile of the proven MFMA dot:
//   accG = sum_k mfma(wa, gb)   (G = W P_b),  accY = sum_k mfma(pa, yb)
//   s += <accG, accY>           (C-layout invariant)
// Total dedup'd traffic ~24 MB (vs ~100 MB in R11, ~200 MB in R12).
// ---------------------------------------------------------------------------
__global__ __launch_bounds__(1024) void fused_kernel(const float* __restrict__ P,
                                                     const float* __restrict__ dhw,
                                                     const float* __restrict__ derr,
                                                     const int*  __restrict__ pairs,
                                                     const float* __restrict__ wts,
                                                     float* __restrict__ ws) {
    extern __shared__ char dynsm[];
    unsigned short* PT = (unsigned short*)(dynsm + OFF_PT);
    unsigned short* AT = (unsigned short*)(dynsm + OFF_AT);
    float*          WF = (float*)(dynsm + OFF_WF);
    __shared__ float redS[16], redT[16];

    const int t = threadIdx.x;
    const int b = blockIdx.x;
    const float* __restrict__ Pb = P + b * 16384;

    // issue P_b load early (latency hides under zero/AT phases)
    float4 pv[4];
    #pragma unroll
    for (int r = 0; r < 4; ++r) pv[r] = ((const float4*)Pb)[t + 1024 * r];

    // zero WF (16896 floats)
    for (int idx = t; idx < 128 * 132; idx += 1024) WF[idx] = 0.f;

    // AT[q][p] = bf16 A_fid[p][q], coalesced float4 reads of dhw/derr
    #pragma unroll
    for (int r = 0; r < 4; ++r) {
        const int f = t + 1024 * r;            // float4 idx [0,4096)
        const int p = f >> 5, c4 = (f & 31) * 4;
        const float4 h = ((const float4*)dhw)[f];
        const float4 e = ((const float4*)derr)[f];
        AT[(c4 + 0) * 136 + p] = f2bf((h.x == 1.0f) ? fmaxf(1.f - e.x, 0.f) : 0.f);
        AT[(c4 + 1) * 136 + p] = f2bf((h.y == 1.0f) ? fmaxf(1.f - e.y, 0.f) : 0.f);
        AT[(c4 + 2) * 136 + p] = f2bf((h.z == 1.0f) ? fmaxf(1.f - e.z, 0.f) : 0.f);
        AT[(c4 + 3) * 136 + p] = f2bf((h.w == 1.0f) ? fmaxf(1.f - e.w, 0.f) : 0.f);
    }

    // PT[q][j] = bf16 P_b[j][q]
    #pragma unroll
    for (int r = 0; r < 4; ++r) {
        const int f = t + 1024 * r;
        const int j = f >> 5, c4 = (f & 31) * 4;
        PT[(c4 + 0) * 136 + j] = f2bf(pv[r].x);
        PT[(c4 + 1) * 136 + j] = f2bf(pv[r].y);
        PT[(c4 + 2) * 136 + j] = f2bf(pv[r].z);
        PT[(c4 + 3) * 136 + j] = f2bf(pv[r].w);
    }
    __syncthreads();                           // WF zeroed before scatter

    // single edge scan: total weight + LDS scatter (distributed atomics)
    float tw = 0.f;
    #pragma unroll 4
    for (int r = 0; r < 8; ++r) {
        const int e2 = t + 1024 * r;           // 2-edge pack, [0,8192)
        const int4   pr = ((const int4*)pairs)[e2];
        const float2 w2 = ((const float2*)wts)[e2];
        tw += w2.x + w2.y;
        atomicAdd(&WF[pr.x * 132 + pr.y], w2.x);
        atomicAdd(&WF[pr.z * 132 + pr.w], w2.y);
    }
    __syncthreads();

    // MFMA phase: wave w -> q-tile qt = w&7, i-tiles [ih*4, ih*4+4)
    const int w    = t >> 6;
    const int lane = t & 63;
    const int l15  = lane & 15;
    const int kb   = (lane >> 4) * 8;
    const int qt   = w & 7, ih = w >> 3;
    const int ncol = qt * 16 + l15;

    short8 gb8[4], yb8[4];
    #pragma unroll
    for (int kk = 0; kk < 4; ++kk) {
        gb8[kk] = *(const short8*)&PT[ncol * 136 + kk * 32 + kb];
        yb8[kk] = *(const short8*)&AT[ncol * 136 + kk * 32 + kb];
    }

    float s = 0.f;
    #pragma unroll
    for (int it = 0; it < 4; ++it) {
        const int mrow = (ih * 4 + it) * 16 + l15;
        f32x4 accG = {0.f, 0.f, 0.f, 0.f};
        f32x4 accY = {0.f, 0.f, 0.f, 0.f};
        #pragma unroll
        for (int kk = 0; kk < 4; ++kk) {
            const int k0 = kk * 32 + kb;
            const short8 wa = pack8(*(const float4*)&WF[mrow * 132 + k0],
                                    *(const float4*)&WF[mrow * 132 + k0 + 4]);
            short8 pa;
            #pragma unroll
            for (int d = 0; d < 8; ++d)
                pa[d] = (short)PT[(k0 + d) * 136 + mrow];
            accG = __builtin_amdgcn_mfma_f32_16x16x32_bf16(wa, gb8[kk], accG, 0, 0, 0);
            accY = __builtin_amdgcn_mfma_f32_16x16x32_bf16(pa, yb8[kk], accY, 0, 0, 0);
        }
        s += accG[0] * accY[0] + accG[1] * accY[1]
           + accG[2] * accY[2] + accG[3] * accY[3];
    }

    // block reduce: s -> WS_PART[b]; tw (full total, every block equal) -> b==0
    #pragma unroll
    for (int off = 32; off; off >>= 1) {
        s  += __shfl_down(s,  off, 64);
        tw += __shfl_down(tw, off, 64);
    }
    if (lane == 0) { redS[w] = s; redT[w] = tw; }
    __syncthreads();
    if (t == 0) {
        float ss = 0.f, tt = 0.f;
        #pragma unroll
        for (int k = 0; k < 16; ++k) { ss += redS[k]; tt += redT[k]; }
        ws[WS_PART + b] = ss;
        if (b == 0) ws[WS_TW] = tt;
    }
}

// finalize for fused path: 1 block x 64 threads
__global__ void fin_kernel(const float* __restrict__ ws, float* __restrict__ out) {
    const int t = threadIdx.x;
    float n = ws[WS_PART + t];
    #pragma unroll
    for (int off = 32; off; off >>= 1) n += __shfl_down(n, off, 64);
    if (t == 0) out[0] = -n / ((float)NB * fmaxf(ws[WS_TW], 1e-8f));
}

// ---------------------------------------------------------------------------
// Fallback path = round-11-proven 24.7 µs structure (256 blocks, static LDS).
// Used only if the dynamic-LDS attribute opt-in fails.
// ---------------------------------------------------------------------------
__global__ __launch_bounds__(512) void fb_main(const float* __restrict__ P,
                                               const float* __restrict__ dhw,
                                               const float* __restrict__ derr,
                                               const int*  __restrict__ pairs,
                                               const float* __restrict__ wts,
                                               float* __restrict__ ws) {
    __shared__ float Wl[32 * 132];
    __shared__ unsigned short Pbl[128 * 136];
    __shared__ float redS[8], redT[8];

    const int t   = threadIdx.x;
    const int blk = blockIdx.x;
    const int b   = blk >> 2;
    const int qtr = blk & 3;
    const float* __restrict__ Pb = P + b * 16384;

    float4 pv[8];
    #pragma unroll
    for (int r = 0; r < 8; ++r) pv[r] = ((const float4*)Pb)[t + 512 * r];
    #pragma unroll
    for (int r = 0; r < 9; ++r) {
        const int idx = t + 512 * r;
        if (idx < 32 * 132) Wl[idx] = 0.f;
    }
    __syncthreads();
    #pragma unroll
    for (int r = 0; r < 8; ++r) {
        const int f = t + 512 * r;
        const int row = f >> 5, c4 = (f & 31) * 4;
        ushort4 u;
        u.x = f2bf(pv[r].x); u.y = f2bf(pv[r].y);
        u.z = f2bf(pv[r].z); u.w = f2bf(pv[r].w);
        *(ushort4*)&Pbl[row * 136 + c4] = u;
    }
    float tw = 0.f;
    #pragma unroll 4
    for (int r = 0; r < 32; ++r) {
        const int e = t + 512 * r;
        const int2 pr = ((const int2*)pairs)[e];
        const float wv = wts[e];
        tw += wv;
        if ((pr.x >> 5) == qtr) atomicAdd(&Wl[(pr.x & 31) * 132 + pr.y], wv);
    }
    __syncthreads();

    const int wv   = t >> 6, lane = t & 63;
    const int l15  = lane & 15, kb = (lane >> 4) * 8;
    const int ncol = wv * 16 + l15;

    short8 gb8[4], yb8[4];
    #pragma unroll
    for (int kk = 0; kk < 4; ++kk) {
        const int k0 = kk * 32 + kb;
        short8 g, y;
        #pragma unroll
        for (int d = 0; d < 8; ++d) {
            g[d] = (short)Pbl[(k0 + d) * 136 + ncol];
            const int ai = (k0 + d) * 128 + ncol;
            const float hw = dhw[ai], er = derr[ai];
            y[d] = (short)f2bf((hw == 1.0f) ? fmaxf(1.0f - er, 0.f) : 0.f);
        }
        gb8[kk] = g; yb8[kk] = y;
    }
    float s = 0.f;
    #pragma unroll
    for (int uu = 0; uu < 2; ++uu) {
        const int lrow = uu * 16 + l15;
        const int mrow = qtr * 32 + lrow;
        f32x4 accG = {0.f, 0.f, 0.f, 0.f};
        f32x4 accY = {0.f, 0.f, 0.f, 0.f};
        #pragma unroll
        for (int kk = 0; kk < 4; ++kk) {
            const int k0 = kk * 32 + kb;
            const short8 wa = pack8(*(const float4*)&Wl[lrow * 132 + k0],
                                    *(const float4*)&Wl[lrow * 132 + k0 + 4]);
            const short8 pa = *(const short8*)&Pbl[mrow * 136 + k0];
            accG = __builtin_amdgcn_mfma_f32_16x16x32_bf16(wa, gb8[kk], accG, 0, 0, 0);
            accY = __builtin_amdgcn_mfma_f32_16x16x32_bf16(pa, yb8[kk], accY, 0, 0, 0);
        }
        s += accG[0] * accY[0] + accG[1] * accY[1]
           + accG[2] * accY[2] + accG[3] * accY[3];
    }
    #pragma unroll
    for (int off = 32; off; off >>= 1) {
        s  += __shfl_down(s,  off, 64);
        tw += __shfl_down(tw, off, 64);
    }
    if (lane == 0) { redS[wv] = s; redT[wv] = tw; }
    __syncthreads();
    if (t == 0) {
        float ss = 0.f, tt = 0.f;
        #pragma unroll
        for (int k = 0; k < 8; ++k) { ss += redS[k]; tt += redT[k]; }
        ws[WS_PART + blk] = ss;
        if (blk == 0) ws[WS_TW] = tt;
    }
}

__global__ __launch_bounds__(256) void fb_fin(const float* __restrict__ ws,
                                              float* __restrict__ out) {
    const int t = threadIdx.x, lane = t & 63, wv = t >> 6;
    float n = ws[WS_PART + t];
    #pragma unroll
    for (int off = 32; off; off >>= 1) n += __shfl_down(n, off, 64);
    __shared__ float red[4];
    if (lane == 0) red[wv] = n;
    __syncthreads();
    if (t == 0) {
        const float num = red[0] + red[1] + red[2] + red[3];
        out[0] = -num / ((float)NB * fmaxf(ws[WS_TW], 1e-8f));
    }
}

extern "C" void kernel_launch(void* const* d_in, const int* in_sizes, int n_in,
                              void* d_out, int out_size, void* d_ws, size_t ws_size,
                              hipStream_t stream) {
    const float* P    = (const float*)d_in[0];
    const float* dhw  = (const float*)d_in[1];
    const float* derr = (const float*)d_in[2];
    const int*   prs  = (const int*)d_in[3];
    const float* wts  = (const float*)d_in[4];
    float* ws  = (float*)d_ws;
    float* out = (float*)d_out;

    // Opt in to >64 KB dynamic LDS (idempotent, deterministic, not a stream op)
    hipError_t aerr = hipFuncSetAttribute(
        (const void*)fused_kernel,
        hipFuncAttributeMaxDynamicSharedMemorySize, DYN_BYTES);

    if (aerr == hipSuccess) {
        fused_kernel<<<NB, 1024, DYN_BYTES, stream>>>(P, dhw, derr, prs, wts, ws);
        fin_kernel<<<1, 64, 0, stream>>>(ws, out);
    } else {
        fb_main<<<NB * 4, 512, 0, stream>>>(P, dhw, derr, prs, wts, ws);
        fb_fin<<<1, 256, 0, stream>>>(ws, out);
    }
}

// Round 14
// 22.659 us; speedup vs baseline: 1.9079x; 1.9079x over previous
//
#include <hip/hip_runtime.h>

// Problem constants
#define NB 64
#define NL 128
#define NQ 128
#define NE 16384

// ws float layout
#define WS_TW    0         // total weight (written by prep block 0)
#define WS_PART  8         // 256 per-block numerator partials (ends 264)
#define WS_W     272       // [i][j] 128x128 fp32 W (272*4=1088, 16B aligned)
// ws ushort layout
#define US_ATB   33312     // [q][p] bf16 A^T (byte 66624, 16B aligned)

using short8 = __attribute__((ext_vector_type(8))) short;  // 8 bf16
using f32x4  = __attribute__((ext_vector_type(4))) float;

// fp32 -> bf16 bits, round-to-nearest-even
__device__ inline unsigned short f2bf(float f) {
    const unsigned u = __float_as_uint(f);
    return (unsigned short)((u + 0x7fffu + ((u >> 16) & 1u)) >> 16);
}

__device__ inline short8 pack8(float4 a, float4 b) {
    short8 r;
    r[0] = f2bf(a.x); r[1] = f2bf(a.y); r[2] = f2bf(a.z); r[3] = f2bf(a.w);
    r[4] = f2bf(b.x); r[5] = f2bf(b.y); r[6] = f2bf(b.z); r[7] = f2bf(b.w);
    return r;
}

// ---------------------------------------------------------------------------
// prep: 16 blocks x 512 threads.
//  blk 0-7 : W rows [oct*16, oct*16+16): scan all edges, filtered LDS scatter
//            ([16][132] fp32), write rows to global W. blk 0 also writes TW.
//  blk 8-15: ATB[q][p] = bf16 A_fid[p][q], 2048 elems each (coalesced reads,
//            transposed 2B stores).
// ---------------------------------------------------------------------------
__global__ __launch_bounds__(512) void prep_kernel(const float* __restrict__ dhw,
                                                   const float* __restrict__ derr,
                                                   const int*  __restrict__ pairs,
                                                   const float* __restrict__ wts,
                                                   float* __restrict__ ws) {
    const int t = threadIdx.x, blk = blockIdx.x;

    if (blk < 8) {
        __shared__ float Wl[16 * 132];
        __shared__ float red[8];
        const int oct = blk;
        for (int idx = t; idx < 16 * 132; idx += 512) Wl[idx] = 0.f;
        __syncthreads();

        float tw = 0.f;
        #pragma unroll 4
        for (int r = 0; r < 32; ++r) {
            const int e = t + 512 * r;                 // [0, 16384)
            const int2  pr = ((const int2*)pairs)[e];
            const float w  = wts[e];
            tw += w;
            if ((pr.x >> 4) == oct)
                atomicAdd(&Wl[(pr.x & 15) * 132 + pr.y], w);
        }
        __syncthreads();

        #pragma unroll
        for (int r = 0; r < 4; ++r) {
            const int idx = t + 512 * r;               // [0, 2048)
            const int row = idx >> 7, col = idx & 127;
            ws[WS_W + oct * 2048 + idx] = Wl[row * 132 + col];
        }

        if (oct == 0) {
            #pragma unroll
            for (int off = 32; off; off >>= 1) tw += __shfl_down(tw, off, 64);
            if ((t & 63) == 0) red[t >> 6] = tw;
            __syncthreads();
            if (t == 0) {
                float s = 0.f;
                #pragma unroll
                for (int k = 0; k < 8; ++k) s += red[k];
                ws[WS_TW] = s;
            }
        }
    } else {
        unsigned short* us = (unsigned short*)ws;
        #pragma unroll
        for (int r = 0; r < 4; ++r) {
            const int idx = (blk - 8) * 2048 + t + 512 * r;   // [0, 16384)
            const float hw = dhw[idx], er = derr[idx];
            const float a  = (hw == 1.0f) ? fmaxf(1.0f - er, 0.f) : 0.f;
            const int p = idx >> 7, q = idx & 127;
            us[US_ATB + q * 128 + p] = f2bf(a);
        }
    }
}

// ---------------------------------------------------------------------------
// main: 256 blocks x 512 threads (R11 body minus edge scan / dhw gather).
// block = (b = blk>>2, qtr = blk&3 -> i-rows [qtr*32, qtr*32+32)).
//  1. load full P_b -> LDS bf16 [128][136] (pad: conflict-free rows+cols)
//  2. gb frags from P_b LDS columns; yb frags = contiguous short8 from ATB (L2)
//  3. per i-tile (2): wa from global W rows (L2), pa from P_b LDS rows;
//     accG = W*P_b frag, accY = P_b*A frag (8 MFMA each unit); s += <G,Y>
//  4. block-reduce s -> WS_PART[blk].
// ---------------------------------------------------------------------------
__global__ __launch_bounds__(512) void main_kernel(const float* __restrict__ P,
                                                   float* __restrict__ ws) {
    __shared__ unsigned short Pbl[128 * 136];  // 34816 B bf16 P_b (padded)
    __shared__ float redS[8];

    const int t   = threadIdx.x;
    const int blk = blockIdx.x;                // [0,256)
    const int b   = blk >> 2;
    const int qtr = blk & 3;                   // i-rows [qtr*32, qtr*32+32)
    const float* __restrict__ Pb = P + b * 16384;
    const unsigned short* us = (const unsigned short*)ws;

    // 1. load P_b (coalesced) -> LDS bf16, padded stride 136
    float4 pv[8];
    #pragma unroll
    for (int r = 0; r < 8; ++r) pv[r] = ((const float4*)Pb)[t + 512 * r];
    #pragma unroll
    for (int r = 0; r < 8; ++r) {
        const int f   = t + 512 * r;           // ushort4 unit within [128][128]
        const int row = f >> 5, c4 = (f & 31) * 4;
        ushort4 u;
        u.x = f2bf(pv[r].x); u.y = f2bf(pv[r].y);
        u.z = f2bf(pv[r].z); u.w = f2bf(pv[r].w);
        *(ushort4*)&Pbl[row * 136 + c4] = u;
    }
    __syncthreads();

    const int wv   = t >> 6;                   // wave -> q-tile
    const int lane = t & 63;
    const int l15  = lane & 15;
    const int kb   = (lane >> 4) * 8;
    const int ncol = wv * 16 + l15;

    // 2. B-operand fragments
    short8 gb8[4], yb8[4];
    #pragma unroll
    for (int kk = 0; kk < 4; ++kk) {
        const int k0 = kk * 32 + kb;
        short8 g;
        #pragma unroll
        for (int d = 0; d < 8; ++d)
            g[d] = (short)Pbl[(k0 + d) * 136 + ncol];          // P_b[j][ncol]
        gb8[kk] = g;
        yb8[kk] = *(const short8*)&us[US_ATB + ncol * 128 + k0];  // L2-hot
    }

    // 3. two i-tiles
    float s = 0.f;
    #pragma unroll
    for (int uu = 0; uu < 2; ++uu) {
        const int mrow = qtr * 32 + uu * 16 + l15;             // global i row
        const float* __restrict__ Wrow = ws + WS_W + mrow * 128;
        f32x4 accG = {0.f, 0.f, 0.f, 0.f};
        f32x4 accY = {0.f, 0.f, 0.f, 0.f};
        #pragma unroll
        for (int kk = 0; kk < 4; ++kk) {
            const int k0 = kk * 32 + kb;
            const short8 wa = pack8(*(const float4*)&Wrow[k0],
                                    *(const float4*)&Wrow[k0 + 4]);  // L2-hot
            const short8 pa = *(const short8*)&Pbl[mrow * 136 + k0];
            accG = __builtin_amdgcn_mfma_f32_16x16x32_bf16(wa, gb8[kk], accG, 0, 0, 0);
            accY = __builtin_amdgcn_mfma_f32_16x16x32_bf16(pa, yb8[kk], accY, 0, 0, 0);
        }
        s += accG[0] * accY[0] + accG[1] * accY[1]
           + accG[2] * accY[2] + accG[3] * accY[3];
    }

    // 4. block reduce; one plain store per block
    #pragma unroll
    for (int off = 32; off; off >>= 1) s += __shfl_down(s, off, 64);
    if (lane == 0) redS[wv] = s;
    __syncthreads();
    if (t == 0) {
        float ss = 0.f;
        #pragma unroll
        for (int k = 0; k < 8; ++k) ss += redS[k];
        ws[WS_PART + blk] = ss;                // distinct slot
    }
}

// ---------------------------------------------------------------------------
// finalize: 1 block x 256 threads; loss = -(sum(part)/B)/max(tw,1e-8)
// ---------------------------------------------------------------------------
__global__ __launch_bounds__(256) void finalize_kernel(const float* __restrict__ ws,
                                                       float* __restrict__ out) {
    const int t = threadIdx.x, lane = t & 63, wv = t >> 6;
    float n = ws[WS_PART + t];
    #pragma unroll
    for (int off = 32; off; off >>= 1) n += __shfl_down(n, off, 64);
    __shared__ float red[4];
    if (lane == 0) red[wv] = n;
    __syncthreads();
    if (t == 0) {
        const float num = red[0] + red[1] + red[2] + red[3];
        out[0] = -num / ((float)NB * fmaxf(ws[WS_TW], 1e-8f));
    }
}

extern "C" void kernel_launch(void* const* d_in, const int* in_sizes, int n_in,
                              void* d_out, int out_size, void* d_ws, size_t ws_size,
                              hipStream_t stream) {
    const float* P    = (const float*)d_in[0];
    const float* dhw  = (const float*)d_in[1];
    const float* derr = (const float*)d_in[2];
    const int*   prs  = (const int*)d_in[3];
    const float* wts  = (const float*)d_in[4];
    float* ws  = (float*)d_ws;
    float* out = (float*)d_out;

    prep_kernel<<<16, 512, 0, stream>>>(dhw, derr, prs, wts, ws);
    main_kernel<<<256, 512, 0, stream>>>(P, ws);
    finalize_kernel<<<1, 256, 0, stream>>>(ws, out);
}